// Round 5
// baseline (416.751 us; speedup 1.0000x reference)
//
#include <hip/hip_runtime.h>

#define Bc 1024
#define Tc 512
#define Ic 64
#define Hc 32

// ---------------------------------------------------------------------------
// K1: xpt[b][h][t] = sum_i x[b][t][i]*W_ih[h][i] + b_ih[h]   (TRANSPOSED out)
// 4096 blocks x 128 threads, 128 rows/block (1 row/thread). 32 KB LDS tile
// (XOR-swizzled float4 chunks) -> ~5 blocks/CU (R3's 64 KB tile capped at
// 1 wave/SIMD -> latency-bound, VALUBusy 18%).
// Weight reads at wave-uniform addresses -> s_load path.
// ---------------------------------------------------------------------------
__global__ __launch_bounds__(128) void xproj_kernel(
    const float* __restrict__ x, const float* __restrict__ Wih,
    const float* __restrict__ bih, float* __restrict__ xpt)
{
    __shared__ float4 xs4[128 * 16];   // 32 KB exactly

    const int j = threadIdx.x;
    const int row0 = blockIdx.x * 128;

    // Stage 128 rows x 16 float4 chunks, coalesced global, swizzled LDS.
    const float4* xg = (const float4*)(x + (size_t)row0 * Ic);
#pragma unroll
    for (int m = 0; m < 16; ++m) {
        const int idx = m * 128 + j;
        const int r = idx >> 4;
        const int c = idx & 15;
        xs4[r * 16 + (c ^ (r & 15))] = xg[idx];
    }
    __syncthreads();

    const float4* W4 = (const float4*)Wih;

    float acc[Hc];
#pragma unroll
    for (int hh = 0; hh < Hc; ++hh) acc[hh] = bih[hh];

#pragma unroll 4
    for (int c = 0; c < 16; ++c) {
        const float4 xv = xs4[j * 16 + (c ^ (j & 15))];
#pragma unroll
        for (int hh = 0; hh < Hc; ++hh) {
            const float4 w = W4[hh * 16 + c];   // uniform -> s_load
            acc[hh] = fmaf(xv.x, w.x, fmaf(xv.y, w.y,
                      fmaf(xv.z, w.z, fmaf(xv.w, w.w, acc[hh]))));
        }
    }

    // Transposed store: for fixed h, lanes write consecutive t -> coalesced.
    const int g = row0 + j;
    float* dst = xpt + (((size_t)(g >> 9) * Hc) << 9) + (g & 511);
#pragma unroll
    for (int hh = 0; hh < Hc; ++hh) dst[hh << 9] = acc[hh];
}

// ---------------------------------------------------------------------------
// K2: sequential scan, 1024 blocks x 1 wave, 1 batch/wave (lane h = lane&31;
// upper half mirrors -- readlane is wave-wide so it can't serve 2 batches).
// CRITICAL FIX vs R2/R3: Whh row in 8 NAMED float4 SSA values (R2's
// float whh[32] array went to scratch -- VGPR_Count=32 proved it -- putting
// a global-latency reload chain on every step). Broadcast via v_readlane
// (VALU pipe, no DS ops on the recurrence path). x read 16 steps at a time
// into named float4s, prefetched one block ahead. Per-step ds_write of the
// output partial (fire-and-forget) + one LDS reduce / 16 steps.
// NOTE: macro params must not be named `w`/`x`/etc -- the preprocessor
// substitutes them even after `.` (R4's compile failure).
// ---------------------------------------------------------------------------
#define RL(k) __int_as_float(__builtin_amdgcn_readlane(hb, (k)))
#define RW(qq, wv)                                                            \
    a0 = fmaf(RL(4 * (qq) + 0), (wv).x, a0);                                  \
    a1 = fmaf(RL(4 * (qq) + 1), (wv).y, a1);                                  \
    a2 = fmaf(RL(4 * (qq) + 2), (wv).z, a2);                                  \
    a3 = fmaf(RL(4 * (qq) + 3), (wv).w, a3);

#define STEP(xval, uu)                                                        \
    {                                                                         \
        float a0 = (xval) + bias, a1 = 0.f, a2 = 0.f, a3 = 0.f;               \
        const int hb = __float_as_int(hval);                                  \
        RW(0, w0) RW(1, w1) RW(2, w2) RW(3, w3)                               \
        RW(4, w4) RW(5, w5) RW(6, w6) RW(7, w7)                               \
        const float a = (a0 + a1) + (a2 + a3);                                \
        const float p  = __builtin_amdgcn_exp2f(a * 2.8853900817779268f);     \
        const float rr = __builtin_amdgcn_rcpf(p + 1.0f);                     \
        hval = fmaf(-2.0f, rr, 1.0f);                                         \
        pbuf[lane >> 5][uu][h] = wo * hval;                                   \
    }

__global__ __launch_bounds__(64) void rnn_kernel(
    const float* __restrict__ xpt, const float* __restrict__ h0,
    const float* __restrict__ Whh, const float* __restrict__ bhh,
    const float* __restrict__ Wout, const float* __restrict__ bout,
    float* __restrict__ out)
{
    const int lane = threadIdx.x;
    const int h    = lane & 31;
    const int b    = blockIdx.x;

    __shared__ float pbuf[2][16][34];   // [half][step][h]; stride 34 -> 8B rows

    const float4* wrow = (const float4*)(Whh + h * Hc);
    const float4 w0 = wrow[0], w1 = wrow[1], w2 = wrow[2], w3 = wrow[3],
                 w4 = wrow[4], w5 = wrow[5], w6 = wrow[6], w7 = wrow[7];
    const float bias = bhh[h];
    const float wo   = Wout[h];
    const float bo   = bout[0];

    float hval = h0[(size_t)b * Hc + h];

    const float* xrow = xpt + (((size_t)b * Hc) << 9) + ((size_t)h << 9);
    float* orow = out + (size_t)b * Tc;

    const float4* xr4 = (const float4*)xrow;
    float4 q0 = xr4[0], q1 = xr4[1], q2 = xr4[2], q3 = xr4[3];

    for (int tb = 0; tb < Tc / 16; ++tb) {
        const int tbn = (tb + 1 < Tc / 16) ? tb + 1 : tb;
        const float4* nxt = (const float4*)(xrow + tbn * 16);
        const float4 n0 = nxt[0], n1 = nxt[1], n2 = nxt[2], n3 = nxt[3];

        STEP(q0.x, 0)  STEP(q0.y, 1)  STEP(q0.z, 2)  STEP(q0.w, 3)
        STEP(q1.x, 4)  STEP(q1.y, 5)  STEP(q1.z, 6)  STEP(q1.w, 7)
        STEP(q2.x, 8)  STEP(q2.y, 9)  STEP(q2.z, 10) STEP(q2.w, 11)
        STEP(q3.x, 12) STEP(q3.y, 13) STEP(q3.z, 14) STEP(q3.w, 15)

        __builtin_amdgcn_wave_barrier();

        // lanes 0-15: out[tb*16+u] = sum_h pbuf[0][u][h] + bo; coalesced store
        if (lane < 16) {
            const float2* pr = (const float2*)pbuf[0][lane];
            float2 sa = pr[0], sb = pr[1];
#pragma unroll
            for (int m = 2; m < 16; m += 2) {
                sa.x += pr[m].x;     sa.y += pr[m].y;
                sb.x += pr[m + 1].x; sb.y += pr[m + 1].y;
            }
            orow[tb * 16 + lane] = ((sa.x + sb.x) + (sa.y + sb.y)) + bo;
        }
        __builtin_amdgcn_wave_barrier();

        q0 = n0; q1 = n1; q2 = n2; q3 = n3;
    }

    // h_last: [1, B, H] appended after outs [B, T, 1]
    if (lane < 32) out[(size_t)Bc * Tc + (size_t)b * Hc + h] = hval;
}

extern "C" void kernel_launch(void* const* d_in, const int* in_sizes, int n_in,
                              void* d_out, int out_size, void* d_ws, size_t ws_size,
                              hipStream_t stream) {
    const float* x    = (const float*)d_in[0];
    const float* h0   = (const float*)d_in[1];
    const float* Wih  = (const float*)d_in[2];
    const float* bih  = (const float*)d_in[3];
    const float* Whh  = (const float*)d_in[4];
    const float* bhh  = (const float*)d_in[5];
    const float* Wout = (const float*)d_in[6];
    const float* bout = (const float*)d_in[7];
    float* out = (float*)d_out;
    float* xpt = (float*)d_ws;   // xpt[b][h][t] fp32 = 64 MB scratch

    xproj_kernel<<<(Bc * Tc) / 128, 128, 0, stream>>>(x, Wih, bih, xpt);
    rnn_kernel<<<Bc, 64, 0, stream>>>(xpt, h0, Whh, bhh, Wout, bout, out);
}

// Round 6
// 345.114 us; speedup vs baseline: 1.2076x; 1.2076x over previous
//
#include <hip/hip_runtime.h>

#define Bc 1024
#define Tc 512
#define Ic 64
#define Hc 32

// ---------------------------------------------------------------------------
// K1: xpt[b][h][t] = sum_i x[b][t][i]*W_ih[h][i] + b_ih[h]   (TRANSPOSED out)
// 8192 blocks x 128 threads, 64 rows/block, 16 KB LDS tile -> ~10 blocks/CU
// (R5's 32 KB tile gave 18.5% occupancy, 0.86 TB/s -> concurrency-bound).
// Each thread: 1 row x 16 h = 1024 fma. XOR-swizzled float4 LDS (verified
// conflict-free in R5: SQ_LDS_BANK_CONFLICT=0). Weights wave-uniform.
// ---------------------------------------------------------------------------
__global__ __launch_bounds__(128) void xproj_kernel(
    const float* __restrict__ x, const float* __restrict__ Wih,
    const float* __restrict__ bih, float* __restrict__ xpt)
{
    __shared__ float4 xs4[64 * 16];   // 16 KB

    const int j = threadIdx.x;
    const int row0 = blockIdx.x * 64;

    // Stage 64 rows x 16 float4 chunks (8 per thread), coalesced global.
    const float4* xg = (const float4*)(x + (size_t)row0 * Ic);
#pragma unroll
    for (int m = 0; m < 8; ++m) {
        const int idx = m * 128 + j;
        const int r = idx >> 4;
        const int c = idx & 15;
        xs4[r * 16 + (c ^ (r & 15))] = xg[idx];
    }
    __syncthreads();

    const int rr = j & 63;
    const int hbase = __builtin_amdgcn_readfirstlane((j >> 6) * 16);

    const float4* W4 = (const float4*)Wih;

    float acc[16];
#pragma unroll
    for (int hh = 0; hh < 16; ++hh) acc[hh] = bih[hbase + hh];

#pragma unroll 4
    for (int c = 0; c < 16; ++c) {
        const float4 xv = xs4[rr * 16 + (c ^ (rr & 15))];
#pragma unroll
        for (int hh = 0; hh < 16; ++hh) {
            const float4 w = W4[(hbase + hh) * 16 + c];   // uniform -> s_load
            acc[hh] = fmaf(xv.x, w.x, fmaf(xv.y, w.y,
                      fmaf(xv.z, w.z, fmaf(xv.w, w.w, acc[hh]))));
        }
    }

    // Transposed store: lanes = consecutive t -> coalesced dword stores.
    const int g = row0 + rr;
    float* dst = xpt + (((size_t)(g >> 9) * Hc + hbase) << 9) + (g & 511);
#pragma unroll
    for (int hh = 0; hh < 16; ++hh) dst[hh << 9] = acc[hh];
}

// ---------------------------------------------------------------------------
// K2: sequential scan, 512 blocks x 1 wave, 2 batches/wave (half = lane>>5).
// h-broadcast: ONE ds_write + 8 ds_read_b128 per step -- pays DS latency
// once per step, vs R3/R5's 32 serialized v_readlane+fma pairs (1220
// cyc/step) and R2's 32 serial ds_swizzles (1860). NO __syncthreads
// anywhere in the loop (single wave; DS ops are in-order within a wave), so
// no vmcnt(0) drain: the 16-step x prefetch floats freely (R1's killer).
// ---------------------------------------------------------------------------
#define RWC(hvv, wvv)                                                         \
    a0 = fmaf((hvv).x, (wvv).x, a0);                                          \
    a1 = fmaf((hvv).y, (wvv).y, a1);                                          \
    a2 = fmaf((hvv).z, (wvv).z, a2);                                          \
    a3 = fmaf((hvv).w, (wvv).w, a3);

#define STEP(xval, uu)                                                        \
    {                                                                         \
        hbuf[half][h] = hval;                                                 \
        __builtin_amdgcn_wave_barrier();                                      \
        const float4* hv = (const float4*)hbuf[half];                         \
        const float4 h0v = hv[0], h1v = hv[1], h2v = hv[2], h3v = hv[3],      \
                     h4v = hv[4], h5v = hv[5], h6v = hv[6], h7v = hv[7];      \
        float a0 = (xval) + bias, a1 = 0.f, a2 = 0.f, a3 = 0.f;               \
        RWC(h0v, w0) RWC(h1v, w1) RWC(h2v, w2) RWC(h3v, w3)                   \
        RWC(h4v, w4) RWC(h5v, w5) RWC(h6v, w6) RWC(h7v, w7)                   \
        const float a = (a0 + a1) + (a2 + a3);                                \
        const float p  = __builtin_amdgcn_exp2f(a * 2.8853900817779268f);     \
        const float rr = __builtin_amdgcn_rcpf(p + 1.0f);                     \
        hval = fmaf(-2.0f, rr, 1.0f);                                         \
        pbuf[half][uu][h] = wo * hval;                                        \
        __builtin_amdgcn_wave_barrier();                                      \
    }

__global__ __launch_bounds__(64) void rnn_kernel(
    const float* __restrict__ xpt, const float* __restrict__ h0,
    const float* __restrict__ Whh, const float* __restrict__ bhh,
    const float* __restrict__ Wout, const float* __restrict__ bout,
    float* __restrict__ out)
{
    const int lane = threadIdx.x;
    const int half = lane >> 5;
    const int h    = lane & 31;
    const int b    = blockIdx.x * 2 + half;

    __shared__ float hbuf[2][32];       // h-state broadcast buffer
    __shared__ float pbuf[2][16][34];   // [half][step][h]; 136 B rows (8B ok)

    const float4* wrow = (const float4*)(Whh + h * Hc);
    const float4 w0 = wrow[0], w1 = wrow[1], w2 = wrow[2], w3 = wrow[3],
                 w4 = wrow[4], w5 = wrow[5], w6 = wrow[6], w7 = wrow[7];
    const float bias = bhh[h];
    const float wo   = Wout[h];
    const float bo   = bout[0];

    float hval = h0[(size_t)b * Hc + h];

    const float* xrow = xpt + (((size_t)b * Hc + h) << 9);   // [b][h][t]
    float* orow = out + (size_t)b * Tc;

    const float4* xr4 = (const float4*)xrow;
    float4 q0 = xr4[0], q1 = xr4[1], q2 = xr4[2], q3 = xr4[3];

    for (int tb = 0; tb < Tc / 16; ++tb) {
        const int tbn = (tb + 1 < Tc / 16) ? tb + 1 : tb;
        const float4* nxt = (const float4*)(xrow + tbn * 16);
        const float4 n0 = nxt[0], n1 = nxt[1], n2 = nxt[2], n3 = nxt[3];

        STEP(q0.x, 0)  STEP(q0.y, 1)  STEP(q0.z, 2)  STEP(q0.w, 3)
        STEP(q1.x, 4)  STEP(q1.y, 5)  STEP(q1.z, 6)  STEP(q1.w, 7)
        STEP(q2.x, 8)  STEP(q2.y, 9)  STEP(q2.z, 10) STEP(q2.w, 11)
        STEP(q3.x, 12) STEP(q3.y, 13) STEP(q3.z, 14) STEP(q3.w, 15)

        __builtin_amdgcn_wave_barrier();

        // u = h&15: both halves reduce their own batch; coalesced stores.
        if (h < 16) {
            const float2* pr = (const float2*)pbuf[half][h];
            float2 sa = pr[0], sb = pr[1];
#pragma unroll
            for (int m = 2; m < 16; m += 2) {
                sa.x += pr[m].x;     sa.y += pr[m].y;
                sb.x += pr[m + 1].x; sb.y += pr[m + 1].y;
            }
            orow[tb * 16 + h] = ((sa.x + sb.x) + (sa.y + sb.y)) + bo;
        }
        __builtin_amdgcn_wave_barrier();

        q0 = n0; q1 = n1; q2 = n2; q3 = n3;
    }

    // h_last: [1, B, H] appended after outs [B, T, 1]
    out[(size_t)Bc * Tc + (size_t)b * Hc + h] = hval;
}

extern "C" void kernel_launch(void* const* d_in, const int* in_sizes, int n_in,
                              void* d_out, int out_size, void* d_ws, size_t ws_size,
                              hipStream_t stream) {
    const float* x    = (const float*)d_in[0];
    const float* h0   = (const float*)d_in[1];
    const float* Wih  = (const float*)d_in[2];
    const float* bih  = (const float*)d_in[3];
    const float* Whh  = (const float*)d_in[4];
    const float* bhh  = (const float*)d_in[5];
    const float* Wout = (const float*)d_in[6];
    const float* bout = (const float*)d_in[7];
    float* out = (float*)d_out;
    float* xpt = (float*)d_ws;   // xpt[b][h][t] fp32 = 64 MB scratch

    xproj_kernel<<<(Bc * Tc) / 64, 128, 0, stream>>>(x, Wih, bih, xpt);
    rnn_kernel<<<Bc / 2, 64, 0, stream>>>(xpt, h0, Whh, bhh, Wout, bout, out);
}

// Round 7
// 317.330 us; speedup vs baseline: 1.3133x; 1.0876x over previous
//
#include <hip/hip_runtime.h>

#define Bc 1024
#define Tc 512
#define Ic 64
#define Hc 32

typedef __bf16 bf16x8 __attribute__((ext_vector_type(8)));
typedef float  f32x4  __attribute__((ext_vector_type(4)));

__device__ inline bf16x8 to_bf16x8(float4 u0, float4 u1) {
    bf16x8 t;
    t[0] = (__bf16)u0.x; t[1] = (__bf16)u0.y; t[2] = (__bf16)u0.z; t[3] = (__bf16)u0.w;
    t[4] = (__bf16)u1.x; t[5] = (__bf16)u1.y; t[6] = (__bf16)u1.z; t[7] = (__bf16)u1.w;
    return t;
}

// ---------------------------------------------------------------------------
// K1 (MFMA): xpt[b][h][t] = sum_i x[b*T+t][i]*W_ih[h][i] + b_ih[h].
// [512k x 64] * [64 x 32] GEMM via v_mfma_f32_16x16x32_bf16.
// 2048 blocks x 256 thr (4 waves); block = 256 rows (one b), wave = 4 tiles
// of 16 rows. Layouts (m89/m92/m120-verified):
//   A[m=lane&15][k=quad*8+j]  -> x row (grow+m), i = q*8 + 32*kh  (2 float4)
//   B[n=lane&15][k=quad*8+j]  -> Wih row (m+16*nh) (natural [N][K] = B^T)
//   D: col=lane&15 -> h, row=quad*4+reg -> t  => one dwordx4 per (lane,nh)
// No LDS, no barriers; fp32 accumulate; only inputs rounded to bf16.
// ---------------------------------------------------------------------------
__global__ __launch_bounds__(256) void xproj_kernel(
    const float* __restrict__ x, const float* __restrict__ Wih,
    const float* __restrict__ bih, float* __restrict__ xpt)
{
    const int lane = threadIdx.x & 63;
    const int wav  = threadIdx.x >> 6;
    const int m    = lane & 15;   // A row-in-tile / B n-index
    const int q    = lane >> 4;   // quad -> k-offset q*8

    // B fragments (shared across all tiles): [nh][kh]
    bf16x8 Bf[2][2];
#pragma unroll
    for (int nh = 0; nh < 2; ++nh)
#pragma unroll
        for (int kh = 0; kh < 2; ++kh) {
            const float* wp = Wih + (m + 16 * nh) * Ic + q * 8 + kh * 32;
            Bf[nh][kh] = to_bf16x8(((const float4*)wp)[0], ((const float4*)wp)[1]);
        }

    const float bias0 = bih[m];
    const float bias1 = bih[m + 16];

    const int row0  = blockIdx.x * 256;   // 256-aligned -> single batch b
    const int bidx  = row0 >> 9;
    const int tbase = row0 & 511;

#pragma unroll
    for (int tt = 0; tt < 4; ++tt) {
        const int trow = wav * 64 + tt * 16;
        const int grow = row0 + trow;

        const float* xp0 = x + (size_t)(grow + m) * Ic + q * 8;
        const bf16x8 A0 = to_bf16x8(((const float4*)xp0)[0], ((const float4*)xp0)[1]);
        const bf16x8 A1 = to_bf16x8(((const float4*)(xp0 + 32))[0],
                                    ((const float4*)(xp0 + 32))[1]);

        f32x4 acc0 = {0.f, 0.f, 0.f, 0.f};
        f32x4 acc1 = {0.f, 0.f, 0.f, 0.f};
        acc0 = __builtin_amdgcn_mfma_f32_16x16x32_bf16(A0, Bf[0][0], acc0, 0, 0, 0);
        acc0 = __builtin_amdgcn_mfma_f32_16x16x32_bf16(A1, Bf[0][1], acc0, 0, 0, 0);
        acc1 = __builtin_amdgcn_mfma_f32_16x16x32_bf16(A0, Bf[1][0], acc1, 0, 0, 0);
        acc1 = __builtin_amdgcn_mfma_f32_16x16x32_bf16(A1, Bf[1][1], acc1, 0, 0, 0);

        const int t0 = tbase + trow + q * 4;   // 4 consecutive t per lane
        float* d0 = xpt + (((size_t)(bidx * Hc + m)) << 9) + t0;
        float* d1 = xpt + (((size_t)(bidx * Hc + m + 16)) << 9) + t0;
        *(float4*)d0 = make_float4(acc0[0] + bias0, acc0[1] + bias0,
                                   acc0[2] + bias0, acc0[3] + bias0);
        *(float4*)d1 = make_float4(acc1[0] + bias1, acc1[1] + bias1,
                                   acc1[2] + bias1, acc1[3] + bias1);
    }
}

// ---------------------------------------------------------------------------
// K2: sequential scan (UNCHANGED from R6 -- verified, 111 us).
// 512 blocks x 1 wave, 2 batches/wave. One ds_write + 8 ds_read_b128 per
// step; no __syncthreads anywhere (single wave, in-order DS pipe).
// ---------------------------------------------------------------------------
#define RWC(hvv, wvv)                                                         \
    a0 = fmaf((hvv).x, (wvv).x, a0);                                          \
    a1 = fmaf((hvv).y, (wvv).y, a1);                                          \
    a2 = fmaf((hvv).z, (wvv).z, a2);                                          \
    a3 = fmaf((hvv).w, (wvv).w, a3);

#define STEP(xval, uu)                                                        \
    {                                                                         \
        hbuf[half][h] = hval;                                                 \
        __builtin_amdgcn_wave_barrier();                                      \
        const float4* hv = (const float4*)hbuf[half];                         \
        const float4 h0v = hv[0], h1v = hv[1], h2v = hv[2], h3v = hv[3],      \
                     h4v = hv[4], h5v = hv[5], h6v = hv[6], h7v = hv[7];      \
        float a0 = (xval) + bias, a1 = 0.f, a2 = 0.f, a3 = 0.f;               \
        RWC(h0v, w0) RWC(h1v, w1) RWC(h2v, w2) RWC(h3v, w3)                   \
        RWC(h4v, w4) RWC(h5v, w5) RWC(h6v, w6) RWC(h7v, w7)                   \
        const float a = (a0 + a1) + (a2 + a3);                                \
        const float p  = __builtin_amdgcn_exp2f(a * 2.8853900817779268f);     \
        const float rr = __builtin_amdgcn_rcpf(p + 1.0f);                     \
        hval = fmaf(-2.0f, rr, 1.0f);                                         \
        pbuf[half][uu][h] = wo * hval;                                        \
        __builtin_amdgcn_wave_barrier();                                      \
    }

__global__ __launch_bounds__(64) void rnn_kernel(
    const float* __restrict__ xpt, const float* __restrict__ h0,
    const float* __restrict__ Whh, const float* __restrict__ bhh,
    const float* __restrict__ Wout, const float* __restrict__ bout,
    float* __restrict__ out)
{
    const int lane = threadIdx.x;
    const int half = lane >> 5;
    const int h    = lane & 31;
    const int b    = blockIdx.x * 2 + half;

    __shared__ float hbuf[2][32];       // h-state broadcast buffer
    __shared__ float pbuf[2][16][34];   // [half][step][h]

    const float4* wrow = (const float4*)(Whh + h * Hc);
    const float4 w0 = wrow[0], w1 = wrow[1], w2 = wrow[2], w3 = wrow[3],
                 w4 = wrow[4], w5 = wrow[5], w6 = wrow[6], w7 = wrow[7];
    const float bias = bhh[h];
    const float wo   = Wout[h];
    const float bo   = bout[0];

    float hval = h0[(size_t)b * Hc + h];

    const float* xrow = xpt + (((size_t)b * Hc + h) << 9);   // [b][h][t]
    float* orow = out + (size_t)b * Tc;

    const float4* xr4 = (const float4*)xrow;
    float4 q0 = xr4[0], q1 = xr4[1], q2 = xr4[2], q3 = xr4[3];

    for (int tb = 0; tb < Tc / 16; ++tb) {
        const int tbn = (tb + 1 < Tc / 16) ? tb + 1 : tb;
        const float4* nxt = (const float4*)(xrow + tbn * 16);
        const float4 n0 = nxt[0], n1 = nxt[1], n2 = nxt[2], n3 = nxt[3];

        STEP(q0.x, 0)  STEP(q0.y, 1)  STEP(q0.z, 2)  STEP(q0.w, 3)
        STEP(q1.x, 4)  STEP(q1.y, 5)  STEP(q1.z, 6)  STEP(q1.w, 7)
        STEP(q2.x, 8)  STEP(q2.y, 9)  STEP(q2.z, 10) STEP(q2.w, 11)
        STEP(q3.x, 12) STEP(q3.y, 13) STEP(q3.z, 14) STEP(q3.w, 15)

        __builtin_amdgcn_wave_barrier();

        // u = h&15: both halves reduce their own batch; coalesced stores.
        if (h < 16) {
            const float2* pr = (const float2*)pbuf[half][h];
            float2 sa = pr[0], sb = pr[1];
#pragma unroll
            for (int m = 2; m < 16; m += 2) {
                sa.x += pr[m].x;     sa.y += pr[m].y;
                sb.x += pr[m + 1].x; sb.y += pr[m + 1].y;
            }
            orow[tb * 16 + h] = ((sa.x + sb.x) + (sa.y + sb.y)) + bo;
        }
        __builtin_amdgcn_wave_barrier();

        q0 = n0; q1 = n1; q2 = n2; q3 = n3;
    }

    // h_last: [1, B, H] appended after outs [B, T, 1]
    out[(size_t)Bc * Tc + (size_t)b * Hc + h] = hval;
}

extern "C" void kernel_launch(void* const* d_in, const int* in_sizes, int n_in,
                              void* d_out, int out_size, void* d_ws, size_t ws_size,
                              hipStream_t stream) {
    const float* x    = (const float*)d_in[0];
    const float* h0   = (const float*)d_in[1];
    const float* Wih  = (const float*)d_in[2];
    const float* bih  = (const float*)d_in[3];
    const float* Whh  = (const float*)d_in[4];
    const float* bhh  = (const float*)d_in[5];
    const float* Wout = (const float*)d_in[6];
    const float* bout = (const float*)d_in[7];
    float* out = (float*)d_out;
    float* xpt = (float*)d_ws;   // xpt[b][h][t] fp32 = 64 MB scratch

    xproj_kernel<<<(Bc * Tc) / 256, 256, 0, stream>>>(x, Wih, bih, xpt);
    rnn_kernel<<<Bc / 2, 64, 0, stream>>>(xpt, h0, Whh, bhh, Wout, bout, out);
}

// Round 8
// 274.418 us; speedup vs baseline: 1.5187x; 1.1564x over previous
//
#include <hip/hip_runtime.h>

#define Bc 1024
#define Tc 512
#define Ic 64
#define Hc 32
#define XP 516   // xq row pitch (bf16): 8B-aligned rows, dw-pitch 258 -> 2-way banks

typedef __bf16 bf16x8 __attribute__((ext_vector_type(8)));
typedef __bf16 bf16x4 __attribute__((ext_vector_type(4)));
typedef float  f32x4  __attribute__((ext_vector_type(4)));

__device__ inline bf16x8 to_bf16x8(float4 u0, float4 u1) {
    bf16x8 t;
    t[0] = (__bf16)u0.x; t[1] = (__bf16)u0.y; t[2] = (__bf16)u0.z; t[3] = (__bf16)u0.w;
    t[4] = (__bf16)u1.x; t[5] = (__bf16)u1.y; t[6] = (__bf16)u1.z; t[7] = (__bf16)u1.w;
    return t;
}

// ---------------------------------------------------------------------------
// Fused kernel: 512 blocks x 1 wave, 2 batches/block.
// Phase 1 (R7-verified MFMA tile, layouts verbatim): xq[bb][h][t] =
//   x-proj + b_ih, bf16, built in LDS. 64 tiles of 16 t; per tile 4x
//   v_mfma_f32_16x16x32_bf16; D layout col=lane&15->h, row=q*4+reg->t.
// Phase 2 (R6-verified scan, verbatim logic): per step one ds_write +
//   8 ds_read_b128 h-broadcast; no __syncthreads in the loop; x-buffer now
//   read from LDS xq (4x ds_read_b64 per 16 steps, off critical path).
// No global xq round-trip (R7 spent ~64MB write + 64MB read on it).
// ---------------------------------------------------------------------------
#define RWC(hvv, wvv)                                                         \
    a0 = fmaf((hvv).x, (wvv).x, a0);                                          \
    a1 = fmaf((hvv).y, (wvv).y, a1);                                          \
    a2 = fmaf((hvv).z, (wvv).z, a2);                                          \
    a3 = fmaf((hvv).w, (wvv).w, a3);

#define STEP(xval, uu)                                                        \
    {                                                                         \
        hbuf[half][h] = hval;                                                 \
        __builtin_amdgcn_wave_barrier();                                      \
        const float4* hv = (const float4*)hbuf[half];                         \
        const float4 h0v = hv[0], h1v = hv[1], h2v = hv[2], h3v = hv[3],      \
                     h4v = hv[4], h5v = hv[5], h6v = hv[6], h7v = hv[7];      \
        float a0 = (xval) + bias, a1 = 0.f, a2 = 0.f, a3 = 0.f;               \
        RWC(h0v, w0) RWC(h1v, w1) RWC(h2v, w2) RWC(h3v, w3)                   \
        RWC(h4v, w4) RWC(h5v, w5) RWC(h6v, w6) RWC(h7v, w7)                   \
        const float a = (a0 + a1) + (a2 + a3);                                \
        const float p  = __builtin_amdgcn_exp2f(a * 2.8853900817779268f);     \
        const float rr = __builtin_amdgcn_rcpf(p + 1.0f);                     \
        hval = fmaf(-2.0f, rr, 1.0f);                                         \
        pbuf[half][uu][h] = wo * hval;                                        \
        __builtin_amdgcn_wave_barrier();                                      \
    }

// convert bf16x4 -> float4 (widening, exact)
#define CVT4(dst, src)                                                        \
    dst.x = (float)(src)[0]; dst.y = (float)(src)[1];                         \
    dst.z = (float)(src)[2]; dst.w = (float)(src)[3];

__global__ __launch_bounds__(64) void fused_rnn_kernel(
    const float* __restrict__ x, const float* __restrict__ Wih,
    const float* __restrict__ bih, const float* __restrict__ h0,
    const float* __restrict__ Whh, const float* __restrict__ bhh,
    const float* __restrict__ Wout, const float* __restrict__ bout,
    float* __restrict__ out)
{
    __shared__ __bf16 xq[2][Hc][XP];    // 66048 B
    __shared__ float hbuf[2][32];       // 256 B
    __shared__ float pbuf[2][16][34];   // 4352 B  -> total ~69 KB, 2 blk/CU

    const int lane = threadIdx.x;
    const int half = lane >> 5;
    const int h    = lane & 31;
    const int m    = lane & 15;   // MFMA A-row / B-n index
    const int q    = lane >> 4;   // MFMA quad
    const int b0   = blockIdx.x * 2;

    // ---------------- Phase 1: x-projection into LDS (MFMA) ----------------
    bf16x8 Bf[2][2];
#pragma unroll
    for (int nh = 0; nh < 2; ++nh)
#pragma unroll
        for (int kh = 0; kh < 2; ++kh) {
            const float* wp = Wih + (m + 16 * nh) * Ic + q * 8 + kh * 32;
            Bf[nh][kh] = to_bf16x8(((const float4*)wp)[0], ((const float4*)wp)[1]);
        }
    const float bias0 = bih[m];
    const float bias1 = bih[m + 16];

#pragma unroll 4
    for (int tt = 0; tt < 64; ++tt) {
        const int bb = tt >> 5;         // batch-in-block (wave-uniform)
        const int lt = tt & 31;         // 16-t tile within the batch
        const float* xp0 =
            x + ((size_t)(b0 + bb) * Tc + lt * 16 + m) * Ic + q * 8;
        const bf16x8 A0 = to_bf16x8(((const float4*)xp0)[0],
                                    ((const float4*)xp0)[1]);
        const bf16x8 A1 = to_bf16x8(((const float4*)(xp0 + 32))[0],
                                    ((const float4*)(xp0 + 32))[1]);

        f32x4 acc0 = {0.f, 0.f, 0.f, 0.f};
        f32x4 acc1 = {0.f, 0.f, 0.f, 0.f};
        acc0 = __builtin_amdgcn_mfma_f32_16x16x32_bf16(A0, Bf[0][0], acc0, 0, 0, 0);
        acc0 = __builtin_amdgcn_mfma_f32_16x16x32_bf16(A1, Bf[0][1], acc0, 0, 0, 0);
        acc1 = __builtin_amdgcn_mfma_f32_16x16x32_bf16(A0, Bf[1][0], acc1, 0, 0, 0);
        acc1 = __builtin_amdgcn_mfma_f32_16x16x32_bf16(A1, Bf[1][1], acc1, 0, 0, 0);

        bf16x4 p0, p1;
        p0[0] = (__bf16)(acc0[0] + bias0); p0[1] = (__bf16)(acc0[1] + bias0);
        p0[2] = (__bf16)(acc0[2] + bias0); p0[3] = (__bf16)(acc0[3] + bias0);
        p1[0] = (__bf16)(acc1[0] + bias1); p1[1] = (__bf16)(acc1[1] + bias1);
        p1[2] = (__bf16)(acc1[2] + bias1); p1[3] = (__bf16)(acc1[3] + bias1);
        // D row = q*4+reg -> t within tile; two ds_write_b64 per lane
        *(bf16x4*)&xq[bb][m][lt * 16 + q * 4]      = p0;
        *(bf16x4*)&xq[bb][m + 16][lt * 16 + q * 4] = p1;
    }

    __syncthreads();   // once: drain phase-1, then the scan loop is barrier-free

    // ---------------- Phase 2: sequential scan (R6 logic) ------------------
    const float4* wrow = (const float4*)(Whh + h * Hc);
    const float4 w0 = wrow[0], w1 = wrow[1], w2 = wrow[2], w3 = wrow[3],
                 w4 = wrow[4], w5 = wrow[5], w6 = wrow[6], w7 = wrow[7];
    const float bias = bhh[h];
    const float wo   = Wout[h];
    const float bo   = bout[0];

    float hval = h0[(size_t)(b0 + half) * Hc + h];
    float* orow = out + (size_t)(b0 + half) * Tc;

    const __bf16* xrow = &xq[half][h][0];

    bf16x4 r0 = *(const bf16x4*)(xrow + 0), r1 = *(const bf16x4*)(xrow + 4),
           r2 = *(const bf16x4*)(xrow + 8), r3 = *(const bf16x4*)(xrow + 12);
    float4 q0, q1, q2, q3;
    CVT4(q0, r0) CVT4(q1, r1) CVT4(q2, r2) CVT4(q3, r3)

    for (int tb = 0; tb < Tc / 16; ++tb) {
        const int tbn = (tb + 1 < Tc / 16) ? tb + 1 : tb;
        const __bf16* nx = xrow + tbn * 16;
        const bf16x4 m0 = *(const bf16x4*)(nx + 0),
                     m1 = *(const bf16x4*)(nx + 4),
                     m2 = *(const bf16x4*)(nx + 8),
                     m3 = *(const bf16x4*)(nx + 12);

        STEP(q0.x, 0)  STEP(q0.y, 1)  STEP(q0.z, 2)  STEP(q0.w, 3)
        STEP(q1.x, 4)  STEP(q1.y, 5)  STEP(q1.z, 6)  STEP(q1.w, 7)
        STEP(q2.x, 8)  STEP(q2.y, 9)  STEP(q2.z, 10) STEP(q2.w, 11)
        STEP(q3.x, 12) STEP(q3.y, 13) STEP(q3.z, 14) STEP(q3.w, 15)

        __builtin_amdgcn_wave_barrier();

        // both halves reduce their own batch; coalesced 16-wide stores
        if (h < 16) {
            const float2* pr = (const float2*)pbuf[half][h];
            float2 sa = pr[0], sb = pr[1];
#pragma unroll
            for (int mm = 2; mm < 16; mm += 2) {
                sa.x += pr[mm].x;     sa.y += pr[mm].y;
                sb.x += pr[mm + 1].x; sb.y += pr[mm + 1].y;
            }
            orow[tb * 16 + h] = ((sa.x + sb.x) + (sa.y + sb.y)) + bo;
        }
        __builtin_amdgcn_wave_barrier();

        CVT4(q0, m0) CVT4(q1, m1) CVT4(q2, m2) CVT4(q3, m3)
    }

    // h_last: [1, B, H] appended after outs [B, T, 1]
    out[(size_t)Bc * Tc + (size_t)(b0 + half) * Hc + h] = hval;
}

extern "C" void kernel_launch(void* const* d_in, const int* in_sizes, int n_in,
                              void* d_out, int out_size, void* d_ws, size_t ws_size,
                              hipStream_t stream) {
    const float* x    = (const float*)d_in[0];
    const float* h0   = (const float*)d_in[1];
    const float* Wih  = (const float*)d_in[2];
    const float* bih  = (const float*)d_in[3];
    const float* Whh  = (const float*)d_in[4];
    const float* bhh  = (const float*)d_in[5];
    const float* Wout = (const float*)d_in[6];
    const float* bout = (const float*)d_in[7];
    float* out = (float*)d_out;

    fused_rnn_kernel<<<Bc / 2, 64, 0, stream>>>(x, Wih, bih, h0, Whh, bhh,
                                                Wout, bout, out);
}